// Round 5
// baseline (509.403 us; speedup 1.0000x reference)
//
#include <hip/hip_runtime.h>
#include <math.h>

#define N_NODES   262144
#define N_EDGES   4194304
#define NUM_GRAPHS 1024
#define NBIN      1024         // dst buckets (dst >> 8)
#define BNODE     256          // nodes per bucket
#define CAPB      4608         // fixed capacity per bucket (mean 4096, +8 sigma)
#define EPB       8192         // edges per binning block
#define EPT       32           // edges per binning thread
#define HCAP      2432         // per-half-bucket esrc capacity (mean 2048, +8.5 sigma)

static __device__ __forceinline__ float fast_rcp(float v) {
    return __builtin_amdgcn_rcpf(v);
}

// ---------------------------------------------------------------------------
// K0: pack x (4f) + pos (3f) into one 32B record per node -> single 64B line
// per random src gather in the fused kernel.
// ---------------------------------------------------------------------------
__global__ __launch_bounds__(256) void pack_kernel(
    const float* __restrict__ x, const float* __restrict__ pos,
    float* __restrict__ xp)
{
    int n = blockIdx.x * 256 + threadIdx.x;
    float4 xv = *(const float4*)(x + 4*n);
    float px = pos[3*n+0], py = pos[3*n+1], pz = pos[3*n+2];
    float4* o = (float4*)(xp + 8*n);
    o[0] = xv;
    o[1] = make_float4(px, py, pz, 0.0f);
}

// ---------------------------------------------------------------------------
// K1: binning v2. 512 blocks x 256 thr x 32 edges. LDS-staged scatter:
//   P1 dst hist -> P2 local scan + global cursor alloc -> P3 rank into LDS
//   stage[] grouped by bin -> P4 wave-cooperative write-out (8 lanes/bin,
//   32B-contiguous segments) -- kills the 16B-segment RFO amplification of
//   the direct scatter (round-4 binning ~160us).
// ---------------------------------------------------------------------------
__global__ __launch_bounds__(256) void binning_kernel(
    const int* __restrict__ ei, int* __restrict__ cursor,
    int* __restrict__ staged)
{
    __shared__ int cnt[NBIN];
    __shared__ int lbase[NBIN];
    __shared__ int gbase[NBIN];
    __shared__ int stage[EPB];                 // 32 KB
    __shared__ int wsum[4];

    #pragma unroll
    for (int t = 0; t < NBIN/256; ++t) cnt[t*256 + threadIdx.x] = 0;
    __syncthreads();

    int base = blockIdx.x * EPB;
    int ds[EPT];
    #pragma unroll
    for (int i = 0; i < EPT; ++i) {
        ds[i] = ei[N_EDGES + base + i*256 + threadIdx.x];
        atomicAdd(&cnt[ds[i] >> 8], 1);
    }
    __syncthreads();

    // local exclusive scan (4 bins/thread) + global cursor alloc
    int b0 = 4*threadIdx.x;
    int c0 = cnt[b0], c1 = cnt[b0+1], c2 = cnt[b0+2], c3 = cnt[b0+3];
    int s  = c0 + c1 + c2 + c3;
    int lane = threadIdx.x & 63, wid = threadIdx.x >> 6;
    int inc = s;
    #pragma unroll
    for (int o = 1; o < 64; o <<= 1) {
        int t = __shfl_up(inc, o);
        if (lane >= o) inc += t;
    }
    if (lane == 63) wsum[wid] = inc;
    __syncthreads();
    int wb = 0;
    #pragma unroll
    for (int w = 0; w < 4; ++w) if (w < wid) wb += wsum[w];
    int ex = wb + inc - s;
    lbase[b0]   = ex;
    lbase[b0+1] = ex + c0;
    lbase[b0+2] = ex + c0 + c1;
    lbase[b0+3] = ex + c0 + c1 + c2;
    gbase[b0]   = c0 ? atomicAdd(cursor + b0,     c0) : 0;
    gbase[b0+1] = c1 ? atomicAdd(cursor + b0 + 1, c1) : 0;
    gbase[b0+2] = c2 ? atomicAdd(cursor + b0 + 2, c2) : 0;
    gbase[b0+3] = c3 ? atomicAdd(cursor + b0 + 3, c3) : 0;
    cnt[b0] = 0; cnt[b0+1] = 0; cnt[b0+2] = 0; cnt[b0+3] = 0;
    __syncthreads();

    // rank + stage (src read here: coalesced, overlaps LDS work)
    #pragma unroll
    for (int i = 0; i < EPT; ++i) {
        int src = ei[base + i*256 + threadIdx.x];
        int dst = ds[i];
        int bk  = dst >> 8;
        int r   = atomicAdd(&cnt[bk], 1);
        stage[lbase[bk] + r] = ((dst & 255) << 18) | src;
    }
    __syncthreads();

    // wave-cooperative write-out: 8 lanes per bin, sequential 4B stores ->
    // 32B-contiguous per 8-lane group; L2 merges to full sectors.
    int sub = lane & 7;
    #pragma unroll
    for (int pass = 0; pass < NBIN/32; ++pass) {
        int bk  = pass*32 + wid*8 + (lane >> 3);
        int c   = cnt[bk];
        int lb  = lbase[bk];
        int gb  = gbase[bk];
        int lim = CAPB - gb;                   // ~8-sigma overflow guard
        if (c > lim) c = lim;
        for (int k = sub; k < c; k += 8)
            staged[bk*CAPB + gb + k] = stage[lb + k];
    }
}

// ---------------------------------------------------------------------------
// Per-edge contribution: rows 4..7 (x[src]) + row 8 (dist) of enc_w1, on top
// of the per-node precomputed hd[] (bias + dst rows). silu accumulate.
// ---------------------------------------------------------------------------
static __device__ __forceinline__ void edge_contrib(
    const float* __restrict__ sw1, const float* __restrict__ hd,
    float4 xs, float dist, float* __restrict__ acc)
{
    float h[16];
    #pragma unroll
    for (int j4 = 0; j4 < 4; ++j4) {
        float4 w = *(const float4*)&sw1[4*16 + 4*j4];
        h[4*j4+0] = fmaf(xs.x, w.x, hd[4*j4+0]);
        h[4*j4+1] = fmaf(xs.x, w.y, hd[4*j4+1]);
        h[4*j4+2] = fmaf(xs.x, w.z, hd[4*j4+2]);
        h[4*j4+3] = fmaf(xs.x, w.w, hd[4*j4+3]);
    }
    #pragma unroll
    for (int j4 = 0; j4 < 4; ++j4) {
        float4 w = *(const float4*)&sw1[5*16 + 4*j4];
        h[4*j4+0] = fmaf(xs.y, w.x, h[4*j4+0]);
        h[4*j4+1] = fmaf(xs.y, w.y, h[4*j4+1]);
        h[4*j4+2] = fmaf(xs.y, w.z, h[4*j4+2]);
        h[4*j4+3] = fmaf(xs.y, w.w, h[4*j4+3]);
    }
    #pragma unroll
    for (int j4 = 0; j4 < 4; ++j4) {
        float4 w = *(const float4*)&sw1[6*16 + 4*j4];
        h[4*j4+0] = fmaf(xs.z, w.x, h[4*j4+0]);
        h[4*j4+1] = fmaf(xs.z, w.y, h[4*j4+1]);
        h[4*j4+2] = fmaf(xs.z, w.z, h[4*j4+2]);
        h[4*j4+3] = fmaf(xs.z, w.w, h[4*j4+3]);
    }
    #pragma unroll
    for (int j4 = 0; j4 < 4; ++j4) {
        float4 w = *(const float4*)&sw1[7*16 + 4*j4];
        h[4*j4+0] = fmaf(xs.w, w.x, h[4*j4+0]);
        h[4*j4+1] = fmaf(xs.w, w.y, h[4*j4+1]);
        h[4*j4+2] = fmaf(xs.w, w.z, h[4*j4+2]);
        h[4*j4+3] = fmaf(xs.w, w.w, h[4*j4+3]);
    }
    #pragma unroll
    for (int j4 = 0; j4 < 4; ++j4) {
        float4 w = *(const float4*)&sw1[8*16 + 4*j4];
        h[4*j4+0] = fmaf(dist, w.x, h[4*j4+0]);
        h[4*j4+1] = fmaf(dist, w.y, h[4*j4+1]);
        h[4*j4+2] = fmaf(dist, w.z, h[4*j4+2]);
        h[4*j4+3] = fmaf(dist, w.w, h[4*j4+3]);
    }
    #pragma unroll
    for (int j = 0; j < 16; ++j) {
        float sg = fast_rcp(1.0f + __expf(-h[j]));
        acc[j] = fmaf(h[j], sg, acc[j]);
    }
}

// ---------------------------------------------------------------------------
// K2 (fused): one 128-thread block per HALF-bucket (128 nodes). 4096 blocks.
// Grid was the occupancy cap at 1024 blocks (4/CU); now ~12 blocks/CU fit
// (LDS ~12.6KB), giving ~24 waves/CU to hide gather latency.
// Phase A: filtered LDS counting sort of this half's edges.
// Phase B: per-node register loop (src ids from LDS, 1-line xp gathers).
// Phase C: node MLP + softmax + wave-segmented attention pooling.
// ---------------------------------------------------------------------------
__global__ __launch_bounds__(128, 4) void fused_node_kernel(
    const float* __restrict__ xp,
    const int* __restrict__ cursor, const int* __restrict__ staged,
    const int* __restrict__ batch,
    const float* __restrict__ w1, const float* __restrict__ b1,
    const float* __restrict__ w2, const float* __restrict__ b2,
    const float* __restrict__ pw, const float* __restrict__ pb,
    float* __restrict__ s_out, float* __restrict__ pooled)
{
    __shared__ int esrc[HCAP];                 // 9728 B
    __shared__ int ldeg[128];
    __shared__ int lcur[128];
    __shared__ int wsum2[2];
    __shared__ __align__(16) float sw1[144];
    __shared__ float sb1[16];
    __shared__ __align__(16) float sw2[256];
    __shared__ float sb2[16];
    __shared__ float spw[32];
    __shared__ float spb[2];

    int tid = threadIdx.x;
    for (int i = tid; i < 144; i += 128) sw1[i] = w1[i];
    for (int i = tid; i < 256; i += 128) sw2[i] = w2[i];
    if (tid < 16)  sb1[tid] = b1[tid];
    if (tid >= 16 && tid < 32) sb2[tid - 16] = b2[tid - 16];
    if (tid >= 32 && tid < 64) spw[tid - 32] = pw[tid - 32];
    if (tid >= 64 && tid < 66) spb[tid - 64] = pb[tid - 64];
    ldeg[tid] = 0;
    __syncthreads();

    int bkt   = blockIdx.x >> 1;
    int hbit  = (blockIdx.x & 1) << 7;         // half-select bit of lo
    int cnt   = cursor[bkt]; if (cnt > CAPB) cnt = CAPB;
    int base  = bkt * CAPB;
    int nb0   = bkt * BNODE + hbit;

    // ---- Phase A: filtered counting sort into LDS ----
    for (int i = tid; i < cnt; i += 128) {
        int lo = staged[base + i] >> 18;
        if ((lo & 128) == hbit) atomicAdd(&ldeg[lo & 127], 1);
    }
    __syncthreads();

    int dg   = ldeg[tid];                      // degree of node nb0+tid
    int lane = tid & 63, wid = tid >> 6;
    int inc  = dg;
    #pragma unroll
    for (int o = 1; o < 64; o <<= 1) {
        int t = __shfl_up(inc, o);
        if (lane >= o) inc += t;
    }
    if (lane == 63) wsum2[wid] = inc;
    __syncthreads();
    int r0 = inc - dg + (wid ? wsum2[0] : 0);  // exclusive row offset in esrc
    lcur[tid] = r0;
    __syncthreads();

    for (int i = tid; i < cnt; i += 128) {
        int p  = staged[base + i];             // L2-hot re-read
        int lo = p >> 18;
        if ((lo & 128) == hbit) {
            int r = atomicAdd(&lcur[lo & 127], 1);
            if (r < HCAP) esrc[r] = p & 0x3FFFF;
        }
    }
    __syncthreads();

    // ---- Phase B: per-node gather + edge MLP ----
    int n = nb0 + tid;
    const float4* xp4 = (const float4*)xp;
    float4 xd = xp4[2*n];
    float4 pd = xp4[2*n+1];

    // hd[j] = b1[j] + sum_{i<4} xd_i * w1[i][j]  -- hoisted out of edge loop
    float hd[16];
    #pragma unroll
    for (int j = 0; j < 16; ++j) hd[j] = sb1[j];
    #pragma unroll
    for (int j4 = 0; j4 < 4; ++j4) {
        float4 w0 = *(const float4*)&sw1[0*16 + 4*j4];
        float4 w1r = *(const float4*)&sw1[1*16 + 4*j4];
        float4 w2r = *(const float4*)&sw1[2*16 + 4*j4];
        float4 w3r = *(const float4*)&sw1[3*16 + 4*j4];
        hd[4*j4+0] = fmaf(xd.x, w0.x, hd[4*j4+0]);
        hd[4*j4+1] = fmaf(xd.x, w0.y, hd[4*j4+1]);
        hd[4*j4+2] = fmaf(xd.x, w0.z, hd[4*j4+2]);
        hd[4*j4+3] = fmaf(xd.x, w0.w, hd[4*j4+3]);
        hd[4*j4+0] = fmaf(xd.y, w1r.x, hd[4*j4+0]);
        hd[4*j4+1] = fmaf(xd.y, w1r.y, hd[4*j4+1]);
        hd[4*j4+2] = fmaf(xd.y, w1r.z, hd[4*j4+2]);
        hd[4*j4+3] = fmaf(xd.y, w1r.w, hd[4*j4+3]);
        hd[4*j4+0] = fmaf(xd.z, w2r.x, hd[4*j4+0]);
        hd[4*j4+1] = fmaf(xd.z, w2r.y, hd[4*j4+1]);
        hd[4*j4+2] = fmaf(xd.z, w2r.z, hd[4*j4+2]);
        hd[4*j4+3] = fmaf(xd.z, w2r.w, hd[4*j4+3]);
        hd[4*j4+0] = fmaf(xd.w, w3r.x, hd[4*j4+0]);
        hd[4*j4+1] = fmaf(xd.w, w3r.y, hd[4*j4+1]);
        hd[4*j4+2] = fmaf(xd.w, w3r.z, hd[4*j4+2]);
        hd[4*j4+3] = fmaf(xd.w, w3r.w, hd[4*j4+3]);
    }

    float acc[16];
    #pragma unroll
    for (int j = 0; j < 16; ++j) acc[j] = 0.0f;

    int k = 0;
    for (; k + 2 <= dg; k += 2) {
        int s0 = esrc[r0 + k];
        int s1 = esrc[r0 + k + 1];
        float4 a0 = xp4[2*s0], p0 = xp4[2*s0+1];
        float4 a1 = xp4[2*s1], p1 = xp4[2*s1+1];

        float dx0 = p0.x - pd.x, dy0 = p0.y - pd.y, dz0 = p0.z - pd.z;
        float dist0 = sqrtf(fmaf(dx0, dx0, fmaf(dy0, dy0, dz0*dz0)));
        edge_contrib(sw1, hd, a0, dist0, acc);

        float dx1 = p1.x - pd.x, dy1 = p1.y - pd.y, dz1 = p1.z - pd.z;
        float dist1 = sqrtf(fmaf(dx1, dx1, fmaf(dy1, dy1, dz1*dz1)));
        edge_contrib(sw1, hd, a1, dist1, acc);
    }
    if (k < dg) {
        int s0 = esrc[r0 + k];
        float4 a0 = xp4[2*s0], p0 = xp4[2*s0+1];
        float dx0 = p0.x - pd.x, dy0 = p0.y - pd.y, dz0 = p0.z - pd.z;
        float dist0 = sqrtf(fmaf(dx0, dx0, fmaf(dy0, dy0, dz0*dz0)));
        edge_contrib(sw1, hd, a0, dist0, acc);
    }

    // ---- Phase C: node MLP + softmax + pooling ----
    float c = (float)dg;
    float inv = fast_rcp(fmaxf(c, 1.0f));
    float h[16];
    #pragma unroll
    for (int j = 0; j < 16; ++j) h[j] = c * sb2[j];
    #pragma unroll
    for (int i = 0; i < 16; ++i) {
        float f = acc[i];
        #pragma unroll
        for (int j4 = 0; j4 < 4; ++j4) {
            float4 w = *(const float4*)&sw2[i*16 + 4*j4];
            h[4*j4+0] = fmaf(f, w.x, h[4*j4+0]);
            h[4*j4+1] = fmaf(f, w.y, h[4*j4+1]);
            h[4*j4+2] = fmaf(f, w.z, h[4*j4+2]);
            h[4*j4+3] = fmaf(f, w.w, h[4*j4+3]);
        }
    }
    #pragma unroll
    for (int j = 0; j < 16; ++j) h[j] = fmaxf(h[j] * inv, 0.0f);

    float l0 = spb[0], l1 = spb[1];
    #pragma unroll
    for (int j = 0; j < 16; ++j) {
        l0 = fmaf(h[j], spw[2*j+0], l0);
        l1 = fmaf(h[j], spw[2*j+1], l1);
    }
    float m = fmaxf(l0, l1);
    float e0 = __expf(l0 - m), e1 = __expf(l1 - m);
    float r = fast_rcp(e0 + e1);
    float s0 = e0 * r, s1 = e1 * r;
    s_out[2*n+0] = s0;
    s_out[2*n+1] = s1;

    float w[32];
    #pragma unroll
    for (int j = 0; j < 16; ++j) { w[j] = s0 * h[j]; w[16+j] = s1 * h[j]; }

    int b = batch[n];
    #pragma unroll
    for (int o = 1; o < 64; o <<= 1) {
        int bn = __shfl_down(b, o);
        bool take = (lane + o < 64) && (bn == b);
        #pragma unroll
        for (int cc = 0; cc < 32; ++cc) {
            float vn = __shfl_down(w[cc], o);
            if (take) w[cc] += vn;
        }
    }
    int bp = __shfl_up(b, 1);
    if (lane == 0 || bp != b) {
        float* pg = pooled + 32*b;
        #pragma unroll
        for (int cc = 0; cc < 32; ++cc) unsafeAtomicAdd(pg + cc, w[cc]);
    }
}

// ---------------------------------------------------------------------------
// K3: per-graph heads. z, recon, analytic potential + forces.
// ---------------------------------------------------------------------------
__global__ __launch_bounds__(256) void graph_kernel(
    const float* __restrict__ pooled,
    const float* __restrict__ toz_w, const float* __restrict__ toz_b,
    const float* __restrict__ vp_w1, const float* __restrict__ vp_b1,
    const float* __restrict__ vp_w2, const float* __restrict__ vp_b2,
    const float* __restrict__ bridge_w, const float* __restrict__ bridge_b,
    float* __restrict__ out_recon, float* __restrict__ out_z,
    float* __restrict__ out_forces, float* __restrict__ out_V)
{
    int g = blockIdx.x * 256 + threadIdx.x;
    if (g >= NUM_GRAPHS) return;

    const float* P = pooled + 32*g;
    float z[8];
    #pragma unroll
    for (int k = 0; k < 2; ++k) {
        #pragma unroll
        for (int d = 0; d < 4; ++d) {
            float a = toz_b[d];
            #pragma unroll
            for (int i = 0; i < 16; ++i) a = fmaf(P[16*k+i], toz_w[4*i+d], a);
            z[4*k+d] = a;
        }
    }
    #pragma unroll
    for (int i = 0; i < 8; ++i) out_z[8*g+i] = z[i];

    #pragma unroll
    for (int j = 0; j < 32; ++j) {
        float a = bridge_b[j];
        #pragma unroll
        for (int i = 0; i < 8; ++i) a = fmaf(z[i], bridge_w[32*i+j], a);
        out_recon[32*g+j] = a;
    }

    float d0 = z[0]-z[4], d1 = z[1]-z[5];
    float dd = sqrtf(d0*d0 + d1*d1 + 1e-6f);

    float V = vp_b2[0];
    float dV = 0.0f;
    #pragma unroll
    for (int j = 0; j < 32; ++j) {
        float w1 = vp_w1[j];
        float t  = fmaf(dd, w1, vp_b1[j]);
        float et = __expf(t);
        float sp = __logf(1.0f + et);
        float sg = et / (1.0f + et);
        float w2 = vp_w2[j];
        V  = fmaf(sp, w2, V);
        dV = fmaf(sg * w1, w2, dV);
    }
    out_V[g] = V;

    float scale = dV / dd;
    float gx = scale * d0, gy = scale * d1;
    out_forces[4*g+0] = -gx;
    out_forces[4*g+1] = -gy;
    out_forces[4*g+2] =  gx;
    out_forces[4*g+3] =  gy;
}

// ---------------------------------------------------------------------------
extern "C" void kernel_launch(void* const* d_in, const int* in_sizes, int n_in,
                              void* d_out, int out_size, void* d_ws, size_t ws_size,
                              hipStream_t stream) {
    const float* x        = (const float*)d_in[0];
    const float* pos      = (const float*)d_in[1];
    const int*   ei       = (const int*)  d_in[2];
    const int*   batch    = (const int*)  d_in[3];
    const float* enc_w1   = (const float*)d_in[4];
    const float* enc_b1   = (const float*)d_in[5];
    const float* enc_w2   = (const float*)d_in[6];
    const float* enc_b2   = (const float*)d_in[7];
    const float* pool_w   = (const float*)d_in[8];
    const float* pool_b   = (const float*)d_in[9];
    const float* toz_w    = (const float*)d_in[10];
    const float* toz_b    = (const float*)d_in[11];
    const float* vp_w1    = (const float*)d_in[12];
    const float* vp_b1    = (const float*)d_in[13];
    const float* vp_w2    = (const float*)d_in[14];
    const float* vp_b2    = (const float*)d_in[15];
    const float* bridge_w = (const float*)d_in[16];
    const float* bridge_b = (const float*)d_in[17];

    // workspace layout (4B units), ~27.4 MB
    int*   cursor = (int*)d_ws;                              // 1024
    float* pooled = (float*)d_ws + NBIN;                     // 32768
    int*   staged = (int*)d_ws + NBIN + 32768;               // 1024*4608
    float* xp     = (float*)(staged + (size_t)NBIN*CAPB);    // 2097152

    float* out        = (float*)d_out;
    float* out_recon  = out;                        // 1024*32
    float* out_z      = out_recon + 1024*32;        // 1024*8
    float* out_s      = out_z + 1024*8;             // 262144*2
    float* out_forces = out_s + (size_t)N_NODES*2;  // 1024*4
    float* out_V      = out_forces + 1024*4;        // 1024

    hipMemsetAsync(d_ws, 0, (size_t)(NBIN + 32768) * sizeof(float), stream);

    pack_kernel   <<<N_NODES/256, 256, 0, stream>>>(x, pos, xp);
    binning_kernel<<<N_EDGES/EPB, 256, 0, stream>>>(ei, cursor, staged);
    fused_node_kernel<<<NBIN*2, 128, 0, stream>>>(
        xp, cursor, staged, batch,
        enc_w1, enc_b1, enc_w2, enc_b2, pool_w, pool_b, out_s, pooled);
    graph_kernel<<<NUM_GRAPHS/256, 256, 0, stream>>>(
        pooled, toz_w, toz_b, vp_w1, vp_b1, vp_w2, vp_b2,
        bridge_w, bridge_b, out_recon, out_z, out_forces, out_V);
}

// Round 6
// 289.399 us; speedup vs baseline: 1.7602x; 1.7602x over previous
//
#include <hip/hip_runtime.h>
#include <math.h>

#define N_NODES   262144
#define N_EDGES   4194304
#define NUM_GRAPHS 1024
#define NBIN      1024         // fine buckets (dst >> 8)
#define BNODE     256          // nodes per fine bucket
#define CAPB      4608         // fine bucket capacity (mean 4096, +8 sigma)
#define NCOARSE   32           // coarse buckets (dst >> 13)
#define CCAP      135168       // coarse bucket capacity (mean 131072, +~11 sigma)
#define EPBA      8192         // edges per binning block
#define SUBB      17           // pass-B sub-blocks per coarse bucket (17*8192 > CCAP)

static __device__ __forceinline__ float fast_rcp(float v) {
    return __builtin_amdgcn_rcpf(v);
}

// ---------------------------------------------------------------------------
// K0: pack x (4f) + pos (3f) into one 32B record per node -> single 64B line
// per random src gather in the fused kernel. Runs AFTER binning (xp overlays
// the dead coarse[] buffer).
// ---------------------------------------------------------------------------
__global__ __launch_bounds__(256) void pack_kernel(
    const float* __restrict__ x, const float* __restrict__ pos,
    float* __restrict__ xp)
{
    int n = blockIdx.x * 256 + threadIdx.x;
    float4 xv = *(const float4*)(x + 4*n);
    float px = pos[3*n+0], py = pos[3*n+1], pz = pos[3*n+2];
    float4* o = (float4*)(xp + 8*n);
    o[0] = xv;
    o[1] = make_float4(px, py, pz, 0.0f);
}

// ---------------------------------------------------------------------------
// K1a: coarse radix pass. 512 blocks x 256 thr x 8192 edges. LDS-staged:
// per-block per-bin segments ~256 ints = 1KB contiguous -> full L2 sectors,
// no read-for-ownership amplification (the v1/v2 scatter wrote 16-32B
// fragments into 128B sectors = 4-8x write traffic).
// dst is read twice; the 2nd read is block-local L2-hot.
// ---------------------------------------------------------------------------
__global__ __launch_bounds__(256) void bin_coarse_kernel(
    const int* __restrict__ ei, int* __restrict__ cursorA,
    int* __restrict__ coarse)
{
    __shared__ int cnt[NCOARSE], rcnt[NCOARSE], lbase[NCOARSE], gbase[NCOARSE];
    __shared__ int stage[EPBA];                // 32 KB
    int tid = threadIdx.x;
    if (tid < NCOARSE) { cnt[tid] = 0; rcnt[tid] = 0; }
    __syncthreads();

    int base = blockIdx.x * EPBA;
    #pragma unroll
    for (int i = 0; i < EPBA/256; ++i) {
        int dst = ei[N_EDGES + base + i*256 + tid];
        atomicAdd(&cnt[dst >> 13], 1);
    }
    __syncthreads();

    if (tid < NCOARSE) {
        int c = cnt[tid], inc = c;
        #pragma unroll
        for (int o = 1; o < NCOARSE; o <<= 1) {
            int t = __shfl_up(inc, o);
            if (tid >= o) inc += t;
        }
        lbase[tid] = inc - c;
        gbase[tid] = c ? atomicAdd(cursorA + tid, c) : 0;
    }
    __syncthreads();

    #pragma unroll
    for (int i = 0; i < EPBA/256; ++i) {
        int e   = base + i*256 + tid;
        int dst = ei[N_EDGES + e];             // L2-hot re-read
        int src = ei[e];
        int bk  = dst >> 13;
        int r   = atomicAdd(&rcnt[bk], 1);
        stage[lbase[bk] + r] = ((dst & 8191) << 18) | src;
    }
    __syncthreads();

    // block-cooperative write-out: 1KB contiguous per bin
    for (int bk = 0; bk < NCOARSE; ++bk) {
        int c  = rcnt[bk];
        int lb = lbase[bk];
        int gb = gbase[bk];
        int lim = CCAP - gb; if (c > lim) c = lim;   // stat-impossible guard
        for (int k = tid; k < c; k += 256)
            coarse[bk*CCAP + gb + k] = stage[lb + k];
    }
}

// ---------------------------------------------------------------------------
// K1b: fine radix pass. 32 coarse x 17 sub-blocks. Contiguous coarse read,
// split into 32 fine buckets (dst bits 8..12 = packed bits 26..30), repack
// to ((dst&255)<<18)|src by masking, 1KB-contiguous write-out.
// ---------------------------------------------------------------------------
__global__ __launch_bounds__(256) void bin_fine_kernel(
    const int* __restrict__ cursorA, const int* __restrict__ coarse,
    int* __restrict__ cursor, int* __restrict__ staged)
{
    __shared__ int cnt[32], rcnt[32], lbase[32], gbase[32];
    __shared__ int stage[EPBA];                // 32 KB
    int tid  = threadIdx.x;
    int cb   = blockIdx.x / SUBB;
    int sub  = blockIdx.x % SUBB;
    int cntA = cursorA[cb]; if (cntA > CCAP) cntA = CCAP;
    int start = sub * EPBA;
    int n = cntA - start;
    if (n <= 0) return;                        // uniform across block
    if (n > EPBA) n = EPBA;

    if (tid < 32) { cnt[tid] = 0; rcnt[tid] = 0; }
    __syncthreads();

    const int* cptr = coarse + (size_t)cb * CCAP + start;
    for (int i = tid; i < n; i += 256)
        atomicAdd(&cnt[(cptr[i] >> 26) & 31], 1);
    __syncthreads();

    if (tid < 32) {
        int c = cnt[tid], inc = c;
        #pragma unroll
        for (int o = 1; o < 32; o <<= 1) {
            int t = __shfl_up(inc, o);
            if (tid >= o) inc += t;
        }
        lbase[tid] = inc - c;
        gbase[tid] = c ? atomicAdd(cursor + (cb*32 + tid), c) : 0;
    }
    __syncthreads();

    for (int i = tid; i < n; i += 256) {
        int p  = cptr[i];                      // L2-hot re-read
        int fb = (p >> 26) & 31;
        int r  = atomicAdd(&rcnt[fb], 1);
        stage[lbase[fb] + r] = p & 0x03FFFFFF; // ((dst&255)<<18)|src
    }
    __syncthreads();

    for (int fb = 0; fb < 32; ++fb) {
        int c  = rcnt[fb];
        int lb = lbase[fb];
        int gb = gbase[fb];
        int bkt = cb*32 + fb;
        int lim = CAPB - gb; if (c > lim) c = lim;   // ~8-sigma guard
        for (int k = tid; k < c; k += 256)
            staged[bkt*CAPB + gb + k] = stage[lb + k];
    }
}

// ---------------------------------------------------------------------------
// Per-edge contribution: rows 4..7 (x[src]) + row 8 (dist) of enc_w1, on top
// of the per-node precomputed hd[] (bias + dst rows). silu accumulate.
// ---------------------------------------------------------------------------
static __device__ __forceinline__ void edge_contrib(
    const float* __restrict__ sw1, const float* __restrict__ hd,
    float4 xs, float dist, float* __restrict__ acc)
{
    float h[16];
    #pragma unroll
    for (int j4 = 0; j4 < 4; ++j4) {
        float4 w = *(const float4*)&sw1[4*16 + 4*j4];
        h[4*j4+0] = fmaf(xs.x, w.x, hd[4*j4+0]);
        h[4*j4+1] = fmaf(xs.x, w.y, hd[4*j4+1]);
        h[4*j4+2] = fmaf(xs.x, w.z, hd[4*j4+2]);
        h[4*j4+3] = fmaf(xs.x, w.w, hd[4*j4+3]);
    }
    #pragma unroll
    for (int j4 = 0; j4 < 4; ++j4) {
        float4 w = *(const float4*)&sw1[5*16 + 4*j4];
        h[4*j4+0] = fmaf(xs.y, w.x, h[4*j4+0]);
        h[4*j4+1] = fmaf(xs.y, w.y, h[4*j4+1]);
        h[4*j4+2] = fmaf(xs.y, w.z, h[4*j4+2]);
        h[4*j4+3] = fmaf(xs.y, w.w, h[4*j4+3]);
    }
    #pragma unroll
    for (int j4 = 0; j4 < 4; ++j4) {
        float4 w = *(const float4*)&sw1[6*16 + 4*j4];
        h[4*j4+0] = fmaf(xs.z, w.x, h[4*j4+0]);
        h[4*j4+1] = fmaf(xs.z, w.y, h[4*j4+1]);
        h[4*j4+2] = fmaf(xs.z, w.z, h[4*j4+2]);
        h[4*j4+3] = fmaf(xs.z, w.w, h[4*j4+3]);
    }
    #pragma unroll
    for (int j4 = 0; j4 < 4; ++j4) {
        float4 w = *(const float4*)&sw1[7*16 + 4*j4];
        h[4*j4+0] = fmaf(xs.w, w.x, h[4*j4+0]);
        h[4*j4+1] = fmaf(xs.w, w.y, h[4*j4+1]);
        h[4*j4+2] = fmaf(xs.w, w.z, h[4*j4+2]);
        h[4*j4+3] = fmaf(xs.w, w.w, h[4*j4+3]);
    }
    #pragma unroll
    for (int j4 = 0; j4 < 4; ++j4) {
        float4 w = *(const float4*)&sw1[8*16 + 4*j4];
        h[4*j4+0] = fmaf(dist, w.x, h[4*j4+0]);
        h[4*j4+1] = fmaf(dist, w.y, h[4*j4+1]);
        h[4*j4+2] = fmaf(dist, w.z, h[4*j4+2]);
        h[4*j4+3] = fmaf(dist, w.w, h[4*j4+3]);
    }
    #pragma unroll
    for (int j = 0; j < 16; ++j) {
        float sg = fast_rcp(1.0f + __expf(-h[j]));
        acc[j] = fmaf(h[j], sg, acc[j]);
    }
}

// ---------------------------------------------------------------------------
// K2 (fused): ROUND-4 KNOWN-GOOD CONFIG (112us). One 256-thread block per
// 256-node bucket. Half-bucket 128-thr variant (round 5) exploded FETCH/WRITE
// (944/207 MB) -- do not revisit without new evidence.
// ---------------------------------------------------------------------------
__global__ __launch_bounds__(256, 4) void fused_node_kernel(
    const float* __restrict__ xp,
    const int* __restrict__ cursor, const int* __restrict__ staged,
    const int* __restrict__ batch,
    const float* __restrict__ w1, const float* __restrict__ b1,
    const float* __restrict__ w2, const float* __restrict__ b2,
    const float* __restrict__ pw, const float* __restrict__ pb,
    float* __restrict__ s_out, float* __restrict__ pooled)
{
    __shared__ int esrc[CAPB];                 // 18432 B
    __shared__ int ldeg[BNODE];
    __shared__ int lcur[BNODE];
    __shared__ int wsum[4];
    __shared__ __align__(16) float sw1[144];
    __shared__ float sb1[16];
    __shared__ __align__(16) float sw2[256];
    __shared__ float sb2[16];
    __shared__ float spw[32];
    __shared__ float spb[2];

    if (threadIdx.x < 144) sw1[threadIdx.x] = w1[threadIdx.x];
    if (threadIdx.x >= 144 && threadIdx.x < 160) sb1[threadIdx.x - 144] = b1[threadIdx.x - 144];
    if (threadIdx.x >= 160 && threadIdx.x < 176) sb2[threadIdx.x - 160] = b2[threadIdx.x - 160];
    if (threadIdx.x >= 176 && threadIdx.x < 208) spw[threadIdx.x - 176] = pw[threadIdx.x - 176];
    if (threadIdx.x >= 208 && threadIdx.x < 210) spb[threadIdx.x - 208] = pb[threadIdx.x - 208];
    sw2[threadIdx.x] = w2[threadIdx.x];
    ldeg[threadIdx.x] = 0;
    __syncthreads();

    int bkt  = blockIdx.x;
    int cnt  = cursor[bkt]; if (cnt > CAPB) cnt = CAPB;
    int base = bkt * CAPB;
    int nb0  = bkt * BNODE;

    // ---- Phase A: counting sort into LDS ----
    for (int i = threadIdx.x; i < cnt; i += 256)
        atomicAdd(&ldeg[staged[base + i] >> 18], 1);
    __syncthreads();

    int dg   = ldeg[threadIdx.x];              // degree of node nb0+tid
    int lane = threadIdx.x & 63, wid = threadIdx.x >> 6;
    int inc  = dg;
    #pragma unroll
    for (int o = 1; o < 64; o <<= 1) {
        int t = __shfl_up(inc, o);
        if (lane >= o) inc += t;
    }
    if (lane == 63) wsum[wid] = inc;
    __syncthreads();
    int wb = 0;
    #pragma unroll
    for (int w = 0; w < 4; ++w) if (w < wid) wb += wsum[w];
    int r0 = wb + inc - dg;                    // exclusive row offset in esrc
    lcur[threadIdx.x] = r0;
    __syncthreads();

    for (int i = threadIdx.x; i < cnt; i += 256) {
        int p  = staged[base + i];             // L2-hot re-read
        int lo = p >> 18;
        int r  = atomicAdd(&lcur[lo], 1);
        esrc[r] = p & 0x3FFFF;
    }
    __syncthreads();

    // ---- Phase B: per-node gather + edge MLP ----
    int n = nb0 + threadIdx.x;
    const float4* xp4 = (const float4*)xp;
    float4 xd = xp4[2*n];
    float4 pd = xp4[2*n+1];

    // hd[j] = b1[j] + sum_{i<4} xd_i * w1[i][j]  -- hoisted out of edge loop
    float hd[16];
    #pragma unroll
    for (int j = 0; j < 16; ++j) hd[j] = sb1[j];
    #pragma unroll
    for (int j4 = 0; j4 < 4; ++j4) {
        float4 w0 = *(const float4*)&sw1[0*16 + 4*j4];
        float4 w1r = *(const float4*)&sw1[1*16 + 4*j4];
        float4 w2r = *(const float4*)&sw1[2*16 + 4*j4];
        float4 w3r = *(const float4*)&sw1[3*16 + 4*j4];
        hd[4*j4+0] = fmaf(xd.x, w0.x, hd[4*j4+0]);
        hd[4*j4+1] = fmaf(xd.x, w0.y, hd[4*j4+1]);
        hd[4*j4+2] = fmaf(xd.x, w0.z, hd[4*j4+2]);
        hd[4*j4+3] = fmaf(xd.x, w0.w, hd[4*j4+3]);
        hd[4*j4+0] = fmaf(xd.y, w1r.x, hd[4*j4+0]);
        hd[4*j4+1] = fmaf(xd.y, w1r.y, hd[4*j4+1]);
        hd[4*j4+2] = fmaf(xd.y, w1r.z, hd[4*j4+2]);
        hd[4*j4+3] = fmaf(xd.y, w1r.w, hd[4*j4+3]);
        hd[4*j4+0] = fmaf(xd.z, w2r.x, hd[4*j4+0]);
        hd[4*j4+1] = fmaf(xd.z, w2r.y, hd[4*j4+1]);
        hd[4*j4+2] = fmaf(xd.z, w2r.z, hd[4*j4+2]);
        hd[4*j4+3] = fmaf(xd.z, w2r.w, hd[4*j4+3]);
        hd[4*j4+0] = fmaf(xd.w, w3r.x, hd[4*j4+0]);
        hd[4*j4+1] = fmaf(xd.w, w3r.y, hd[4*j4+1]);
        hd[4*j4+2] = fmaf(xd.w, w3r.z, hd[4*j4+2]);
        hd[4*j4+3] = fmaf(xd.w, w3r.w, hd[4*j4+3]);
    }

    float acc[16];
    #pragma unroll
    for (int j = 0; j < 16; ++j) acc[j] = 0.0f;

    int k = 0;
    for (; k + 2 <= dg; k += 2) {
        int s0 = esrc[r0 + k];
        int s1 = esrc[r0 + k + 1];
        float4 a0 = xp4[2*s0], p0 = xp4[2*s0+1];
        float4 a1 = xp4[2*s1], p1 = xp4[2*s1+1];

        float dx0 = p0.x - pd.x, dy0 = p0.y - pd.y, dz0 = p0.z - pd.z;
        float dist0 = sqrtf(fmaf(dx0, dx0, fmaf(dy0, dy0, dz0*dz0)));
        edge_contrib(sw1, hd, a0, dist0, acc);

        float dx1 = p1.x - pd.x, dy1 = p1.y - pd.y, dz1 = p1.z - pd.z;
        float dist1 = sqrtf(fmaf(dx1, dx1, fmaf(dy1, dy1, dz1*dz1)));
        edge_contrib(sw1, hd, a1, dist1, acc);
    }
    if (k < dg) {
        int s0 = esrc[r0 + k];
        float4 a0 = xp4[2*s0], p0 = xp4[2*s0+1];
        float dx0 = p0.x - pd.x, dy0 = p0.y - pd.y, dz0 = p0.z - pd.z;
        float dist0 = sqrtf(fmaf(dx0, dx0, fmaf(dy0, dy0, dz0*dz0)));
        edge_contrib(sw1, hd, a0, dist0, acc);
    }

    // ---- Phase C: node MLP + softmax + pooling ----
    float c = (float)dg;
    float inv = fast_rcp(fmaxf(c, 1.0f));
    float h[16];
    #pragma unroll
    for (int j = 0; j < 16; ++j) h[j] = c * sb2[j];
    #pragma unroll
    for (int i = 0; i < 16; ++i) {
        float f = acc[i];
        #pragma unroll
        for (int j4 = 0; j4 < 4; ++j4) {
            float4 w = *(const float4*)&sw2[i*16 + 4*j4];
            h[4*j4+0] = fmaf(f, w.x, h[4*j4+0]);
            h[4*j4+1] = fmaf(f, w.y, h[4*j4+1]);
            h[4*j4+2] = fmaf(f, w.z, h[4*j4+2]);
            h[4*j4+3] = fmaf(f, w.w, h[4*j4+3]);
        }
    }
    #pragma unroll
    for (int j = 0; j < 16; ++j) h[j] = fmaxf(h[j] * inv, 0.0f);

    float l0 = spb[0], l1 = spb[1];
    #pragma unroll
    for (int j = 0; j < 16; ++j) {
        l0 = fmaf(h[j], spw[2*j+0], l0);
        l1 = fmaf(h[j], spw[2*j+1], l1);
    }
    float m = fmaxf(l0, l1);
    float e0 = __expf(l0 - m), e1 = __expf(l1 - m);
    float r = fast_rcp(e0 + e1);
    float s0 = e0 * r, s1 = e1 * r;
    s_out[2*n+0] = s0;
    s_out[2*n+1] = s1;

    float w[32];
    #pragma unroll
    for (int j = 0; j < 16; ++j) { w[j] = s0 * h[j]; w[16+j] = s1 * h[j]; }

    int b = batch[n];
    #pragma unroll
    for (int o = 1; o < 64; o <<= 1) {
        int bn = __shfl_down(b, o);
        bool take = (lane + o < 64) && (bn == b);
        #pragma unroll
        for (int cc = 0; cc < 32; ++cc) {
            float vn = __shfl_down(w[cc], o);
            if (take) w[cc] += vn;
        }
    }
    int bp = __shfl_up(b, 1);
    if (lane == 0 || bp != b) {
        float* pg = pooled + 32*b;
        #pragma unroll
        for (int cc = 0; cc < 32; ++cc) unsafeAtomicAdd(pg + cc, w[cc]);
    }
}

// ---------------------------------------------------------------------------
// K3: per-graph heads. z, recon, analytic potential + forces.
// ---------------------------------------------------------------------------
__global__ __launch_bounds__(256) void graph_kernel(
    const float* __restrict__ pooled,
    const float* __restrict__ toz_w, const float* __restrict__ toz_b,
    const float* __restrict__ vp_w1, const float* __restrict__ vp_b1,
    const float* __restrict__ vp_w2, const float* __restrict__ vp_b2,
    const float* __restrict__ bridge_w, const float* __restrict__ bridge_b,
    float* __restrict__ out_recon, float* __restrict__ out_z,
    float* __restrict__ out_forces, float* __restrict__ out_V)
{
    int g = blockIdx.x * 256 + threadIdx.x;
    if (g >= NUM_GRAPHS) return;

    const float* P = pooled + 32*g;
    float z[8];
    #pragma unroll
    for (int k = 0; k < 2; ++k) {
        #pragma unroll
        for (int d = 0; d < 4; ++d) {
            float a = toz_b[d];
            #pragma unroll
            for (int i = 0; i < 16; ++i) a = fmaf(P[16*k+i], toz_w[4*i+d], a);
            z[4*k+d] = a;
        }
    }
    #pragma unroll
    for (int i = 0; i < 8; ++i) out_z[8*g+i] = z[i];

    #pragma unroll
    for (int j = 0; j < 32; ++j) {
        float a = bridge_b[j];
        #pragma unroll
        for (int i = 0; i < 8; ++i) a = fmaf(z[i], bridge_w[32*i+j], a);
        out_recon[32*g+j] = a;
    }

    float d0 = z[0]-z[4], d1 = z[1]-z[5];
    float dd = sqrtf(d0*d0 + d1*d1 + 1e-6f);

    float V = vp_b2[0];
    float dV = 0.0f;
    #pragma unroll
    for (int j = 0; j < 32; ++j) {
        float w1 = vp_w1[j];
        float t  = fmaf(dd, w1, vp_b1[j]);
        float et = __expf(t);
        float sp = __logf(1.0f + et);
        float sg = et / (1.0f + et);
        float w2 = vp_w2[j];
        V  = fmaf(sp, w2, V);
        dV = fmaf(sg * w1, w2, dV);
    }
    out_V[g] = V;

    float scale = dV / dd;
    float gx = scale * d0, gy = scale * d1;
    out_forces[4*g+0] = -gx;
    out_forces[4*g+1] = -gy;
    out_forces[4*g+2] =  gx;
    out_forces[4*g+3] =  gy;
}

// ---------------------------------------------------------------------------
extern "C" void kernel_launch(void* const* d_in, const int* in_sizes, int n_in,
                              void* d_out, int out_size, void* d_ws, size_t ws_size,
                              hipStream_t stream) {
    const float* x        = (const float*)d_in[0];
    const float* pos      = (const float*)d_in[1];
    const int*   ei       = (const int*)  d_in[2];
    const int*   batch    = (const int*)  d_in[3];
    const float* enc_w1   = (const float*)d_in[4];
    const float* enc_b1   = (const float*)d_in[5];
    const float* enc_w2   = (const float*)d_in[6];
    const float* enc_b2   = (const float*)d_in[7];
    const float* pool_w   = (const float*)d_in[8];
    const float* pool_b   = (const float*)d_in[9];
    const float* toz_w    = (const float*)d_in[10];
    const float* toz_b    = (const float*)d_in[11];
    const float* vp_w1    = (const float*)d_in[12];
    const float* vp_b1    = (const float*)d_in[13];
    const float* vp_w2    = (const float*)d_in[14];
    const float* vp_b2    = (const float*)d_in[15];
    const float* bridge_w = (const float*)d_in[16];
    const float* bridge_b = (const float*)d_in[17];

    // workspace layout (4B units), ~36.3 MB; xp overlays dead coarse[]
    int*   cursorA = (int*)d_ws;                                  // 32
    int*   cursor  = cursorA + NCOARSE;                           // 1024
    float* pooled  = (float*)(cursor + NBIN);                     // 32768
    int*   staged  = (int*)pooled + 32768;                        // 1024*4608
    int*   coarse  = staged + (size_t)NBIN*CAPB;                  // 32*135168
    float* xp      = (float*)coarse;                              // 2097152 (alias)

    float* out        = (float*)d_out;
    float* out_recon  = out;                        // 1024*32
    float* out_z      = out_recon + 1024*32;        // 1024*8
    float* out_s      = out_z + 1024*8;             // 262144*2
    float* out_forces = out_s + (size_t)N_NODES*2;  // 1024*4
    float* out_V      = out_forces + 1024*4;        // 1024

    hipMemsetAsync(d_ws, 0, (size_t)(NCOARSE + NBIN + 32768) * sizeof(float), stream);

    bin_coarse_kernel<<<N_EDGES/EPBA, 256, 0, stream>>>(ei, cursorA, coarse);
    bin_fine_kernel  <<<NCOARSE*SUBB, 256, 0, stream>>>(cursorA, coarse, cursor, staged);
    pack_kernel      <<<N_NODES/256, 256, 0, stream>>>(x, pos, xp);
    fused_node_kernel<<<NBIN, 256, 0, stream>>>(
        xp, cursor, staged, batch,
        enc_w1, enc_b1, enc_w2, enc_b2, pool_w, pool_b, out_s, pooled);
    graph_kernel<<<NUM_GRAPHS/256, 256, 0, stream>>>(
        pooled, toz_w, toz_b, vp_w1, vp_b1, vp_w2, vp_b2,
        bridge_w, bridge_b, out_recon, out_z, out_forces, out_V);
}

// Round 7
// 272.509 us; speedup vs baseline: 1.8693x; 1.0620x over previous
//
#include <hip/hip_runtime.h>
#include <math.h>

#define N_NODES   262144
#define N_EDGES   4194304
#define NUM_GRAPHS 1024
#define NBIN      1024         // fine buckets (dst >> 8)
#define BNODE     256          // nodes per fine bucket
#define CAPB      4608         // fine bucket capacity (mean 4096, +8 sigma)
#define NCOARSE   32           // coarse buckets (dst >> 13)
#define EPBA      4096         // edges per binning block (16KB stage -> 4 blk/CU)
#define SUBB      33           // pass-B sub-blocks per coarse bucket
#define CCAP      (SUBB*EPBA)  // 135168: coarse capacity (mean 131072, +11 sigma)

static __device__ __forceinline__ float fast_rcp(float v) {
    return __builtin_amdgcn_rcpf(v);
}

// ---------------------------------------------------------------------------
// K0: pack x (4f) + pos (3f) into one 32B record per node -> single 64B line
// per random src gather in the fused kernel. Runs AFTER binning (xp overlays
// the dead coarse[] buffer).
// ---------------------------------------------------------------------------
__global__ __launch_bounds__(256) void pack_kernel(
    const float* __restrict__ x, const float* __restrict__ pos,
    float* __restrict__ xp)
{
    int n = blockIdx.x * 256 + threadIdx.x;
    float4 xv = *(const float4*)(x + 4*n);
    float px = pos[3*n+0], py = pos[3*n+1], pz = pos[3*n+2];
    float4* o = (float4*)(xp + 8*n);
    o[0] = xv;
    o[1] = make_float4(px, py, pz, 0.0f);
}

// ---------------------------------------------------------------------------
// K1a: coarse radix pass. 1024 blocks x 256 thr x 4096 edges.
// v3: int4 loads (16B/lane, 4x MLP), dst kept in regs (single dst read),
// 16KB stage -> 4 blocks/CU (vs 2) = 2x waves to hide stream latency.
// Round-6 version (scalar loads, 2 blk/CU) was latency-bound at ~75us.
// ---------------------------------------------------------------------------
__global__ __launch_bounds__(256) void bin_coarse_kernel(
    const int* __restrict__ ei, int* __restrict__ cursorA,
    int* __restrict__ coarse)
{
    __shared__ int cnt[NCOARSE], rcnt[NCOARSE], lbase[NCOARSE], gbase[NCOARSE];
    __shared__ int stage[EPBA];                // 16 KB
    int tid = threadIdx.x;
    if (tid < NCOARSE) { cnt[tid] = 0; rcnt[tid] = 0; }
    __syncthreads();

    int base = blockIdx.x * EPBA;
    const int4* d4 = (const int4*)(ei + N_EDGES + base);
    const int4* s4 = (const int4*)(ei + base);

    int4 dv[4];
    #pragma unroll
    for (int i = 0; i < 4; ++i) {
        dv[i] = d4[i*256 + tid];
        atomicAdd(&cnt[dv[i].x >> 13], 1);
        atomicAdd(&cnt[dv[i].y >> 13], 1);
        atomicAdd(&cnt[dv[i].z >> 13], 1);
        atomicAdd(&cnt[dv[i].w >> 13], 1);
    }
    __syncthreads();

    if (tid < NCOARSE) {
        int c = cnt[tid], inc = c;
        #pragma unroll
        for (int o = 1; o < NCOARSE; o <<= 1) {
            int t = __shfl_up(inc, o);
            if (tid >= o) inc += t;
        }
        lbase[tid] = inc - c;
        gbase[tid] = c ? atomicAdd(cursorA + tid, c) : 0;
    }
    __syncthreads();

    #pragma unroll
    for (int i = 0; i < 4; ++i) {
        int4 sv = s4[i*256 + tid];
        int d, s, bk, r;
        d = dv[i].x; s = sv.x; bk = d >> 13; r = atomicAdd(&rcnt[bk], 1);
        stage[lbase[bk] + r] = ((d & 8191) << 18) | s;
        d = dv[i].y; s = sv.y; bk = d >> 13; r = atomicAdd(&rcnt[bk], 1);
        stage[lbase[bk] + r] = ((d & 8191) << 18) | s;
        d = dv[i].z; s = sv.z; bk = d >> 13; r = atomicAdd(&rcnt[bk], 1);
        stage[lbase[bk] + r] = ((d & 8191) << 18) | s;
        d = dv[i].w; s = sv.w; bk = d >> 13; r = atomicAdd(&rcnt[bk], 1);
        stage[lbase[bk] + r] = ((d & 8191) << 18) | s;
    }
    __syncthreads();

    // block-cooperative write-out: ~512B contiguous per bin
    for (int bk = 0; bk < NCOARSE; ++bk) {
        int c  = rcnt[bk];
        int lb = lbase[bk];
        int gb = gbase[bk];
        int lim = CCAP - gb; if (c > lim) c = lim;   // stat-impossible guard
        for (int k = tid; k < c; k += 256)
            coarse[bk*CCAP + gb + k] = stage[lb + k];
    }
}

// ---------------------------------------------------------------------------
// K1b: fine radix pass. 32 coarse x 33 sub-blocks (1056 blocks). int4 loads
// of the contiguous coarse slice; split into 32 fine buckets (packed bits
// 26..30 = dst bits 8..12); repack to ((dst&255)<<18)|src; write-out.
// ---------------------------------------------------------------------------
__global__ __launch_bounds__(256) void bin_fine_kernel(
    const int* __restrict__ cursorA, const int* __restrict__ coarse,
    int* __restrict__ cursor, int* __restrict__ staged)
{
    int tid  = threadIdx.x;
    int cb   = blockIdx.x / SUBB;
    int sub  = blockIdx.x % SUBB;
    int cntA = cursorA[cb]; if (cntA > CCAP) cntA = CCAP;
    int start = sub * EPBA;
    int n = cntA - start;
    if (n <= 0) return;                        // uniform across block
    if (n > EPBA) n = EPBA;

    __shared__ int cnt[32], rcnt[32], lbase[32], gbase[32];
    __shared__ int stage[EPBA];                // 16 KB
    if (tid < 32) { cnt[tid] = 0; rcnt[tid] = 0; }
    __syncthreads();

    const int* cptr = coarse + (size_t)cb * CCAP + start;
    const int4* c4  = (const int4*)cptr;
    int nv = n >> 2;

    for (int i = tid; i < nv; i += 256) {
        int4 p = c4[i];
        atomicAdd(&cnt[(p.x >> 26) & 31], 1);
        atomicAdd(&cnt[(p.y >> 26) & 31], 1);
        atomicAdd(&cnt[(p.z >> 26) & 31], 1);
        atomicAdd(&cnt[(p.w >> 26) & 31], 1);
    }
    for (int i = (nv << 2) + tid; i < n; i += 256)
        atomicAdd(&cnt[(cptr[i] >> 26) & 31], 1);
    __syncthreads();

    if (tid < 32) {
        int c = cnt[tid], inc = c;
        #pragma unroll
        for (int o = 1; o < 32; o <<= 1) {
            int t = __shfl_up(inc, o);
            if (tid >= o) inc += t;
        }
        lbase[tid] = inc - c;
        gbase[tid] = c ? atomicAdd(cursor + (cb*32 + tid), c) : 0;
    }
    __syncthreads();

    for (int i = tid; i < nv; i += 256) {
        int4 p = c4[i];
        int fb, r;
        fb = (p.x >> 26) & 31; r = atomicAdd(&rcnt[fb], 1);
        stage[lbase[fb] + r] = p.x & 0x03FFFFFF;
        fb = (p.y >> 26) & 31; r = atomicAdd(&rcnt[fb], 1);
        stage[lbase[fb] + r] = p.y & 0x03FFFFFF;
        fb = (p.z >> 26) & 31; r = atomicAdd(&rcnt[fb], 1);
        stage[lbase[fb] + r] = p.z & 0x03FFFFFF;
        fb = (p.w >> 26) & 31; r = atomicAdd(&rcnt[fb], 1);
        stage[lbase[fb] + r] = p.w & 0x03FFFFFF;
    }
    for (int i = (nv << 2) + tid; i < n; i += 256) {
        int p  = cptr[i];
        int fb = (p >> 26) & 31;
        int r  = atomicAdd(&rcnt[fb], 1);
        stage[lbase[fb] + r] = p & 0x03FFFFFF;
    }
    __syncthreads();

    for (int fb = 0; fb < 32; ++fb) {
        int c  = rcnt[fb];
        int lb = lbase[fb];
        int gb = gbase[fb];
        int bkt = cb*32 + fb;
        int lim = CAPB - gb; if (c > lim) c = lim;   // ~8-sigma guard
        for (int k = tid; k < c; k += 256)
            staged[bkt*CAPB + gb + k] = stage[lb + k];
    }
}

// ---------------------------------------------------------------------------
// Per-edge contribution: rows 4..7 (x[src]) + row 8 (dist) of enc_w1, on top
// of the per-node precomputed hd[] (bias + dst rows). silu accumulate.
// ---------------------------------------------------------------------------
static __device__ __forceinline__ void edge_contrib(
    const float* __restrict__ sw1, const float* __restrict__ hd,
    float4 xs, float dist, float* __restrict__ acc)
{
    float h[16];
    #pragma unroll
    for (int j4 = 0; j4 < 4; ++j4) {
        float4 w = *(const float4*)&sw1[4*16 + 4*j4];
        h[4*j4+0] = fmaf(xs.x, w.x, hd[4*j4+0]);
        h[4*j4+1] = fmaf(xs.x, w.y, hd[4*j4+1]);
        h[4*j4+2] = fmaf(xs.x, w.z, hd[4*j4+2]);
        h[4*j4+3] = fmaf(xs.x, w.w, hd[4*j4+3]);
    }
    #pragma unroll
    for (int j4 = 0; j4 < 4; ++j4) {
        float4 w = *(const float4*)&sw1[5*16 + 4*j4];
        h[4*j4+0] = fmaf(xs.y, w.x, h[4*j4+0]);
        h[4*j4+1] = fmaf(xs.y, w.y, h[4*j4+1]);
        h[4*j4+2] = fmaf(xs.y, w.z, h[4*j4+2]);
        h[4*j4+3] = fmaf(xs.y, w.w, h[4*j4+3]);
    }
    #pragma unroll
    for (int j4 = 0; j4 < 4; ++j4) {
        float4 w = *(const float4*)&sw1[6*16 + 4*j4];
        h[4*j4+0] = fmaf(xs.z, w.x, h[4*j4+0]);
        h[4*j4+1] = fmaf(xs.z, w.y, h[4*j4+1]);
        h[4*j4+2] = fmaf(xs.z, w.z, h[4*j4+2]);
        h[4*j4+3] = fmaf(xs.z, w.w, h[4*j4+3]);
    }
    #pragma unroll
    for (int j4 = 0; j4 < 4; ++j4) {
        float4 w = *(const float4*)&sw1[7*16 + 4*j4];
        h[4*j4+0] = fmaf(xs.w, w.x, h[4*j4+0]);
        h[4*j4+1] = fmaf(xs.w, w.y, h[4*j4+1]);
        h[4*j4+2] = fmaf(xs.w, w.z, h[4*j4+2]);
        h[4*j4+3] = fmaf(xs.w, w.w, h[4*j4+3]);
    }
    #pragma unroll
    for (int j4 = 0; j4 < 4; ++j4) {
        float4 w = *(const float4*)&sw1[8*16 + 4*j4];
        h[4*j4+0] = fmaf(dist, w.x, h[4*j4+0]);
        h[4*j4+1] = fmaf(dist, w.y, h[4*j4+1]);
        h[4*j4+2] = fmaf(dist, w.z, h[4*j4+2]);
        h[4*j4+3] = fmaf(dist, w.w, h[4*j4+3]);
    }
    #pragma unroll
    for (int j = 0; j < 16; ++j) {
        float sg = fast_rcp(1.0f + __expf(-h[j]));
        acc[j] = fmaf(h[j], sg, acc[j]);
    }
}

// ---------------------------------------------------------------------------
// K2 (fused): ROUND-4 KNOWN-GOOD CONFIG (112us) -- UNTOUCHED this round so
// the binning delta is cleanly attributable.
// ---------------------------------------------------------------------------
__global__ __launch_bounds__(256, 4) void fused_node_kernel(
    const float* __restrict__ xp,
    const int* __restrict__ cursor, const int* __restrict__ staged,
    const int* __restrict__ batch,
    const float* __restrict__ w1, const float* __restrict__ b1,
    const float* __restrict__ w2, const float* __restrict__ b2,
    const float* __restrict__ pw, const float* __restrict__ pb,
    float* __restrict__ s_out, float* __restrict__ pooled)
{
    __shared__ int esrc[CAPB];                 // 18432 B
    __shared__ int ldeg[BNODE];
    __shared__ int lcur[BNODE];
    __shared__ int wsum[4];
    __shared__ __align__(16) float sw1[144];
    __shared__ float sb1[16];
    __shared__ __align__(16) float sw2[256];
    __shared__ float sb2[16];
    __shared__ float spw[32];
    __shared__ float spb[2];

    if (threadIdx.x < 144) sw1[threadIdx.x] = w1[threadIdx.x];
    if (threadIdx.x >= 144 && threadIdx.x < 160) sb1[threadIdx.x - 144] = b1[threadIdx.x - 144];
    if (threadIdx.x >= 160 && threadIdx.x < 176) sb2[threadIdx.x - 160] = b2[threadIdx.x - 160];
    if (threadIdx.x >= 176 && threadIdx.x < 208) spw[threadIdx.x - 176] = pw[threadIdx.x - 176];
    if (threadIdx.x >= 208 && threadIdx.x < 210) spb[threadIdx.x - 208] = pb[threadIdx.x - 208];
    sw2[threadIdx.x] = w2[threadIdx.x];
    ldeg[threadIdx.x] = 0;
    __syncthreads();

    int bkt  = blockIdx.x;
    int cnt  = cursor[bkt]; if (cnt > CAPB) cnt = CAPB;
    int base = bkt * CAPB;
    int nb0  = bkt * BNODE;

    // ---- Phase A: counting sort into LDS ----
    for (int i = threadIdx.x; i < cnt; i += 256)
        atomicAdd(&ldeg[staged[base + i] >> 18], 1);
    __syncthreads();

    int dg   = ldeg[threadIdx.x];              // degree of node nb0+tid
    int lane = threadIdx.x & 63, wid = threadIdx.x >> 6;
    int inc  = dg;
    #pragma unroll
    for (int o = 1; o < 64; o <<= 1) {
        int t = __shfl_up(inc, o);
        if (lane >= o) inc += t;
    }
    if (lane == 63) wsum[wid] = inc;
    __syncthreads();
    int wb = 0;
    #pragma unroll
    for (int w = 0; w < 4; ++w) if (w < wid) wb += wsum[w];
    int r0 = wb + inc - dg;                    // exclusive row offset in esrc
    lcur[threadIdx.x] = r0;
    __syncthreads();

    for (int i = threadIdx.x; i < cnt; i += 256) {
        int p  = staged[base + i];             // L2-hot re-read
        int lo = p >> 18;
        int r  = atomicAdd(&lcur[lo], 1);
        esrc[r] = p & 0x3FFFF;
    }
    __syncthreads();

    // ---- Phase B: per-node gather + edge MLP ----
    int n = nb0 + threadIdx.x;
    const float4* xp4 = (const float4*)xp;
    float4 xd = xp4[2*n];
    float4 pd = xp4[2*n+1];

    // hd[j] = b1[j] + sum_{i<4} xd_i * w1[i][j]  -- hoisted out of edge loop
    float hd[16];
    #pragma unroll
    for (int j = 0; j < 16; ++j) hd[j] = sb1[j];
    #pragma unroll
    for (int j4 = 0; j4 < 4; ++j4) {
        float4 w0 = *(const float4*)&sw1[0*16 + 4*j4];
        float4 w1r = *(const float4*)&sw1[1*16 + 4*j4];
        float4 w2r = *(const float4*)&sw1[2*16 + 4*j4];
        float4 w3r = *(const float4*)&sw1[3*16 + 4*j4];
        hd[4*j4+0] = fmaf(xd.x, w0.x, hd[4*j4+0]);
        hd[4*j4+1] = fmaf(xd.x, w0.y, hd[4*j4+1]);
        hd[4*j4+2] = fmaf(xd.x, w0.z, hd[4*j4+2]);
        hd[4*j4+3] = fmaf(xd.x, w0.w, hd[4*j4+3]);
        hd[4*j4+0] = fmaf(xd.y, w1r.x, hd[4*j4+0]);
        hd[4*j4+1] = fmaf(xd.y, w1r.y, hd[4*j4+1]);
        hd[4*j4+2] = fmaf(xd.y, w1r.z, hd[4*j4+2]);
        hd[4*j4+3] = fmaf(xd.y, w1r.w, hd[4*j4+3]);
        hd[4*j4+0] = fmaf(xd.z, w2r.x, hd[4*j4+0]);
        hd[4*j4+1] = fmaf(xd.z, w2r.y, hd[4*j4+1]);
        hd[4*j4+2] = fmaf(xd.z, w2r.z, hd[4*j4+2]);
        hd[4*j4+3] = fmaf(xd.z, w2r.w, hd[4*j4+3]);
        hd[4*j4+0] = fmaf(xd.w, w3r.x, hd[4*j4+0]);
        hd[4*j4+1] = fmaf(xd.w, w3r.y, hd[4*j4+1]);
        hd[4*j4+2] = fmaf(xd.w, w3r.z, hd[4*j4+2]);
        hd[4*j4+3] = fmaf(xd.w, w3r.w, hd[4*j4+3]);
    }

    float acc[16];
    #pragma unroll
    for (int j = 0; j < 16; ++j) acc[j] = 0.0f;

    int k = 0;
    for (; k + 2 <= dg; k += 2) {
        int s0 = esrc[r0 + k];
        int s1 = esrc[r0 + k + 1];
        float4 a0 = xp4[2*s0], p0 = xp4[2*s0+1];
        float4 a1 = xp4[2*s1], p1 = xp4[2*s1+1];

        float dx0 = p0.x - pd.x, dy0 = p0.y - pd.y, dz0 = p0.z - pd.z;
        float dist0 = sqrtf(fmaf(dx0, dx0, fmaf(dy0, dy0, dz0*dz0)));
        edge_contrib(sw1, hd, a0, dist0, acc);

        float dx1 = p1.x - pd.x, dy1 = p1.y - pd.y, dz1 = p1.z - pd.z;
        float dist1 = sqrtf(fmaf(dx1, dx1, fmaf(dy1, dy1, dz1*dz1)));
        edge_contrib(sw1, hd, a1, dist1, acc);
    }
    if (k < dg) {
        int s0 = esrc[r0 + k];
        float4 a0 = xp4[2*s0], p0 = xp4[2*s0+1];
        float dx0 = p0.x - pd.x, dy0 = p0.y - pd.y, dz0 = p0.z - pd.z;
        float dist0 = sqrtf(fmaf(dx0, dx0, fmaf(dy0, dy0, dz0*dz0)));
        edge_contrib(sw1, hd, a0, dist0, acc);
    }

    // ---- Phase C: node MLP + softmax + pooling ----
    float c = (float)dg;
    float inv = fast_rcp(fmaxf(c, 1.0f));
    float h[16];
    #pragma unroll
    for (int j = 0; j < 16; ++j) h[j] = c * sb2[j];
    #pragma unroll
    for (int i = 0; i < 16; ++i) {
        float f = acc[i];
        #pragma unroll
        for (int j4 = 0; j4 < 4; ++j4) {
            float4 w = *(const float4*)&sw2[i*16 + 4*j4];
            h[4*j4+0] = fmaf(f, w.x, h[4*j4+0]);
            h[4*j4+1] = fmaf(f, w.y, h[4*j4+1]);
            h[4*j4+2] = fmaf(f, w.z, h[4*j4+2]);
            h[4*j4+3] = fmaf(f, w.w, h[4*j4+3]);
        }
    }
    #pragma unroll
    for (int j = 0; j < 16; ++j) h[j] = fmaxf(h[j] * inv, 0.0f);

    float l0 = spb[0], l1 = spb[1];
    #pragma unroll
    for (int j = 0; j < 16; ++j) {
        l0 = fmaf(h[j], spw[2*j+0], l0);
        l1 = fmaf(h[j], spw[2*j+1], l1);
    }
    float m = fmaxf(l0, l1);
    float e0 = __expf(l0 - m), e1 = __expf(l1 - m);
    float r = fast_rcp(e0 + e1);
    float s0 = e0 * r, s1 = e1 * r;
    s_out[2*n+0] = s0;
    s_out[2*n+1] = s1;

    float w[32];
    #pragma unroll
    for (int j = 0; j < 16; ++j) { w[j] = s0 * h[j]; w[16+j] = s1 * h[j]; }

    int b = batch[n];
    #pragma unroll
    for (int o = 1; o < 64; o <<= 1) {
        int bn = __shfl_down(b, o);
        bool take = (lane + o < 64) && (bn == b);
        #pragma unroll
        for (int cc = 0; cc < 32; ++cc) {
            float vn = __shfl_down(w[cc], o);
            if (take) w[cc] += vn;
        }
    }
    int bp = __shfl_up(b, 1);
    if (lane == 0 || bp != b) {
        float* pg = pooled + 32*b;
        #pragma unroll
        for (int cc = 0; cc < 32; ++cc) unsafeAtomicAdd(pg + cc, w[cc]);
    }
}

// ---------------------------------------------------------------------------
// K3: per-graph heads. z, recon, analytic potential + forces.
// ---------------------------------------------------------------------------
__global__ __launch_bounds__(256) void graph_kernel(
    const float* __restrict__ pooled,
    const float* __restrict__ toz_w, const float* __restrict__ toz_b,
    const float* __restrict__ vp_w1, const float* __restrict__ vp_b1,
    const float* __restrict__ vp_w2, const float* __restrict__ vp_b2,
    const float* __restrict__ bridge_w, const float* __restrict__ bridge_b,
    float* __restrict__ out_recon, float* __restrict__ out_z,
    float* __restrict__ out_forces, float* __restrict__ out_V)
{
    int g = blockIdx.x * 256 + threadIdx.x;
    if (g >= NUM_GRAPHS) return;

    const float* P = pooled + 32*g;
    float z[8];
    #pragma unroll
    for (int k = 0; k < 2; ++k) {
        #pragma unroll
        for (int d = 0; d < 4; ++d) {
            float a = toz_b[d];
            #pragma unroll
            for (int i = 0; i < 16; ++i) a = fmaf(P[16*k+i], toz_w[4*i+d], a);
            z[4*k+d] = a;
        }
    }
    #pragma unroll
    for (int i = 0; i < 8; ++i) out_z[8*g+i] = z[i];

    #pragma unroll
    for (int j = 0; j < 32; ++j) {
        float a = bridge_b[j];
        #pragma unroll
        for (int i = 0; i < 8; ++i) a = fmaf(z[i], bridge_w[32*i+j], a);
        out_recon[32*g+j] = a;
    }

    float d0 = z[0]-z[4], d1 = z[1]-z[5];
    float dd = sqrtf(d0*d0 + d1*d1 + 1e-6f);

    float V = vp_b2[0];
    float dV = 0.0f;
    #pragma unroll
    for (int j = 0; j < 32; ++j) {
        float w1 = vp_w1[j];
        float t  = fmaf(dd, w1, vp_b1[j]);
        float et = __expf(t);
        float sp = __logf(1.0f + et);
        float sg = et / (1.0f + et);
        float w2 = vp_w2[j];
        V  = fmaf(sp, w2, V);
        dV = fmaf(sg * w1, w2, dV);
    }
    out_V[g] = V;

    float scale = dV / dd;
    float gx = scale * d0, gy = scale * d1;
    out_forces[4*g+0] = -gx;
    out_forces[4*g+1] = -gy;
    out_forces[4*g+2] =  gx;
    out_forces[4*g+3] =  gy;
}

// ---------------------------------------------------------------------------
extern "C" void kernel_launch(void* const* d_in, const int* in_sizes, int n_in,
                              void* d_out, int out_size, void* d_ws, size_t ws_size,
                              hipStream_t stream) {
    const float* x        = (const float*)d_in[0];
    const float* pos      = (const float*)d_in[1];
    const int*   ei       = (const int*)  d_in[2];
    const int*   batch    = (const int*)  d_in[3];
    const float* enc_w1   = (const float*)d_in[4];
    const float* enc_b1   = (const float*)d_in[5];
    const float* enc_w2   = (const float*)d_in[6];
    const float* enc_b2   = (const float*)d_in[7];
    const float* pool_w   = (const float*)d_in[8];
    const float* pool_b   = (const float*)d_in[9];
    const float* toz_w    = (const float*)d_in[10];
    const float* toz_b    = (const float*)d_in[11];
    const float* vp_w1    = (const float*)d_in[12];
    const float* vp_b1    = (const float*)d_in[13];
    const float* vp_w2    = (const float*)d_in[14];
    const float* vp_b2    = (const float*)d_in[15];
    const float* bridge_w = (const float*)d_in[16];
    const float* bridge_b = (const float*)d_in[17];

    // workspace layout (4B units), ~36.3 MB; xp overlays dead coarse[]
    int*   cursorA = (int*)d_ws;                                  // 32
    int*   cursor  = cursorA + NCOARSE;                           // 1024
    float* pooled  = (float*)(cursor + NBIN);                     // 32768
    int*   staged  = (int*)pooled + 32768;                        // 1024*4608
    int*   coarse  = staged + (size_t)NBIN*CAPB;                  // 32*135168
    float* xp      = (float*)coarse;                              // 2097152 (alias)

    float* out        = (float*)d_out;
    float* out_recon  = out;                        // 1024*32
    float* out_z      = out_recon + 1024*32;        // 1024*8
    float* out_s      = out_z + 1024*8;             // 262144*2
    float* out_forces = out_s + (size_t)N_NODES*2;  // 1024*4
    float* out_V      = out_forces + 1024*4;        // 1024

    hipMemsetAsync(d_ws, 0, (size_t)(NCOARSE + NBIN + 32768) * sizeof(float), stream);

    bin_coarse_kernel<<<N_EDGES/EPBA, 256, 0, stream>>>(ei, cursorA, coarse);
    bin_fine_kernel  <<<NCOARSE*SUBB, 256, 0, stream>>>(cursorA, coarse, cursor, staged);
    pack_kernel      <<<N_NODES/256, 256, 0, stream>>>(x, pos, xp);
    fused_node_kernel<<<NBIN, 256, 0, stream>>>(
        xp, cursor, staged, batch,
        enc_w1, enc_b1, enc_w2, enc_b2, pool_w, pool_b, out_s, pooled);
    graph_kernel<<<NUM_GRAPHS/256, 256, 0, stream>>>(
        pooled, toz_w, toz_b, vp_w1, vp_b1, vp_w2, vp_b2,
        bridge_w, bridge_b, out_recon, out_z, out_forces, out_V);
}